// Round 1
// baseline (230.593 us; speedup 1.0000x reference)
//
#include <hip/hip_runtime.h>

#define H_DIM 4096
#define NHEADS 4
#define DH 1024
#define NROWS 1024

typedef __attribute__((ext_vector_type(8))) short short8;
typedef __attribute__((ext_vector_type(4))) short short4v;
typedef __attribute__((ext_vector_type(4))) float f32x4;

__device__ __forceinline__ short f2bf(float f) {
  union { float f; unsigned u; } v; v.f = f;
  unsigned r = v.u + 0x7fffu + ((v.u >> 16) & 1u);
  return (short)(r >> 16);
}
__device__ __forceinline__ float bf2f(short s) {
  union { unsigned u; float f; } v;
  v.u = ((unsigned)(unsigned short)s) << 16;
  return v.f;
}

// ---------------- Phase 1: QKV projection GEMMs ----------------
// C[n,f] = sum_d A[n,d] * W[h,d,f] + bias[h,f], stored bf16 to ws.
// 12 GEMMs (qkv*4+h), each M=1024,N=1024,K=4096, tiles 128x128, BK=32.
__launch_bounds__(256, 2)
__global__ void qkv_gemm(const float* __restrict__ node1,
                         const float* __restrict__ node2,
                         const float* __restrict__ Wq, const float* __restrict__ bq,
                         const float* __restrict__ Wk, const float* __restrict__ bk,
                         const float* __restrict__ Wv, const float* __restrict__ bv,
                         short* __restrict__ qkv_out) {
  const int gid = blockIdx.x;
  const int gemm = gid >> 6;            // 0..11
  const int tile = gid & 63;
  const int qkv = gemm >> 2;            // 0=q,1=k,2=v
  const int h = gemm & 3;
  const float* A = (qkv == 0) ? node1 : node2;
  const float* W = (qkv == 0) ? Wq : (qkv == 1 ? Wk : Wv);
  const float* bias = (qkv == 0) ? bq : (qkv == 1 ? bk : bv);
  const float* B = W + (size_t)h * H_DIM * DH;
  const float* bh = bias + h * DH;
  short* C = qkv_out + (size_t)gemm * NROWS * DH;

  const int bm0 = (tile >> 3) * 128;
  const int bn0 = (tile & 7) * 128;

  __shared__ short As[128][40];   // [row][k], pad to 40 (80B stride, 16B aligned)
  __shared__ short Bs[128][40];   // [f][k]  (transposed B tile)

  const int t = threadIdx.x;
  const int lane = t & 63;
  const int w = t >> 6;
  const int wm = (w >> 1) * 64;
  const int wn = (w & 1) * 64;
  const int lr = lane & 15;
  const int lk = lane >> 4;

  // staging assignment
  const int ar = t >> 3;          // A row 0..31 (+32p)
  const int ac = (t & 7) * 4;     // A col (float4)
  const int bfc = t & 127;        // B f-column 0..127
  const int bd = (t >> 7) * 16;   // B d-base 0 or 16

  f32x4 acc[4][4];
#pragma unroll
  for (int m = 0; m < 4; ++m)
#pragma unroll
    for (int n = 0; n < 4; ++n)
      acc[m][n] = (f32x4)(0.0f);

  f32x4 rA[4];
  float rB[16];

  const float* Abase = A + (size_t)bm0 * H_DIM;
  const float* Bbase = B + bn0 + bfc;

  // prefetch tile 0
#pragma unroll
  for (int p = 0; p < 4; ++p)
    rA[p] = *(const f32x4*)&Abase[(size_t)(ar + 32 * p) * H_DIM + ac];
#pragma unroll
  for (int i = 0; i < 16; ++i)
    rB[i] = Bbase[(size_t)(bd + i) * DH];

  const int NKT = H_DIM / 32;   // 128
  for (int kt = 0; kt < NKT; ++kt) {
    __syncthreads();
    // regs -> LDS (convert f32 -> bf16)
#pragma unroll
    for (int p = 0; p < 4; ++p) {
      short4v s;
      s.x = f2bf(rA[p].x); s.y = f2bf(rA[p].y);
      s.z = f2bf(rA[p].z); s.w = f2bf(rA[p].w);
      *(short4v*)&As[ar + 32 * p][ac] = s;
    }
    {
      short8 lo, hi;
#pragma unroll
      for (int i = 0; i < 8; ++i) { lo[i] = f2bf(rB[i]); hi[i] = f2bf(rB[8 + i]); }
      *(short8*)&Bs[bfc][bd] = lo;
      *(short8*)&Bs[bfc][bd + 8] = hi;
    }
    __syncthreads();
    // prefetch next tile (overlaps MFMA below)
    if (kt + 1 < NKT) {
      const int k0 = (kt + 1) * 32;
#pragma unroll
      for (int p = 0; p < 4; ++p)
        rA[p] = *(const f32x4*)&Abase[(size_t)(ar + 32 * p) * H_DIM + k0 + ac];
#pragma unroll
      for (int i = 0; i < 16; ++i)
        rB[i] = Bbase[(size_t)(k0 + bd + i) * DH];
    }
    short8 af[4], bf_[4];
#pragma unroll
    for (int m = 0; m < 4; ++m)
      af[m] = *(const short8*)&As[wm + m * 16 + lr][lk * 8];
#pragma unroll
    for (int n = 0; n < 4; ++n)
      bf_[n] = *(const short8*)&Bs[wn + n * 16 + lr][lk * 8];
#pragma unroll
    for (int m = 0; m < 4; ++m)
#pragma unroll
      for (int n = 0; n < 4; ++n)
        acc[m][n] = __builtin_amdgcn_mfma_f32_16x16x32_bf16(af[m], bf_[n], acc[m][n], 0, 0, 0);
  }

  // epilogue: + bias, -> bf16
#pragma unroll
  for (int n = 0; n < 4; ++n) {
    const int col = bn0 + wn + n * 16 + lr;
    const float bv_ = bh[col];
#pragma unroll
    for (int m = 0; m < 4; ++m) {
      const int row0 = bm0 + wm + m * 16 + lk * 4;
#pragma unroll
      for (int r = 0; r < 4; ++r)
        C[(size_t)(row0 + r) * DH + col] = f2bf(acc[m][n][r] + bv_);
    }
  }
}

// ---------------- Phase 2: S = Q*K^T, r = S*scale*V, write pre-LN f32 ----------------
__launch_bounds__(256, 2)
__global__ void attn_gemm(const short* __restrict__ qb, const short* __restrict__ kb,
                          const short* __restrict__ vb, float* __restrict__ out) {
  const int gid = blockIdx.x;
  const int h = gid >> 6;
  const int tile = gid & 63;
  const int bm0 = (tile >> 3) * 128;
  const int bn0 = (tile & 7) * 128;
  const short* Q = qb + (size_t)h * NROWS * DH;
  const short* K = kb + (size_t)h * NROWS * DH;
  const short* V = vb + (size_t)h * NROWS * DH;

  __shared__ short As[128][40];
  __shared__ short Bs[128][40];

  const int t = threadIdx.x;
  const int lane = t & 63;
  const int w = t >> 6;
  const int wm = (w >> 1) * 64;
  const int wn = (w & 1) * 64;
  const int lr = lane & 15;
  const int lk = lane >> 4;

  const int sr = t >> 2;          // 0..63 (+64p)
  const int sc = (t & 3) * 8;     // 0,8,16,24

  f32x4 acc[4][4];
#pragma unroll
  for (int m = 0; m < 4; ++m)
#pragma unroll
    for (int n = 0; n < 4; ++n)
      acc[m][n] = (f32x4)(0.0f);

  short8 rA[2], rB[2];
#pragma unroll
  for (int p = 0; p < 2; ++p) {
    rA[p] = *(const short8*)&Q[(size_t)(bm0 + sr + 64 * p) * DH + sc];
    rB[p] = *(const short8*)&K[(size_t)(bn0 + sr + 64 * p) * DH + sc];
  }

  const int NKT = DH / 32;   // 32
  for (int kt = 0; kt < NKT; ++kt) {
    __syncthreads();
#pragma unroll
    for (int p = 0; p < 2; ++p) {
      *(short8*)&As[sr + 64 * p][sc] = rA[p];
      *(short8*)&Bs[sr + 64 * p][sc] = rB[p];
    }
    __syncthreads();
    if (kt + 1 < NKT) {
      const int k0 = (kt + 1) * 32;
#pragma unroll
      for (int p = 0; p < 2; ++p) {
        rA[p] = *(const short8*)&Q[(size_t)(bm0 + sr + 64 * p) * DH + k0 + sc];
        rB[p] = *(const short8*)&K[(size_t)(bn0 + sr + 64 * p) * DH + k0 + sc];
      }
    }
    short8 af[4], bf_[4];
#pragma unroll
    for (int m = 0; m < 4; ++m)
      af[m] = *(const short8*)&As[wm + m * 16 + lr][lk * 8];
#pragma unroll
    for (int n = 0; n < 4; ++n)
      bf_[n] = *(const short8*)&Bs[wn + n * 16 + lr][lk * 8];
#pragma unroll
    for (int m = 0; m < 4; ++m)
#pragma unroll
      for (int n = 0; n < 4; ++n)
        acc[m][n] = __builtin_amdgcn_mfma_f32_16x16x32_bf16(af[m], bf_[n], acc[m][n], 0, 0, 0);
  }

  const float scale = 0.03125f;  // 1/sqrt(1024)
#pragma unroll
  for (int n = 0; n < 4; ++n) {
    const int col = bn0 + wn + n * 16 + lr;
#pragma unroll
    for (int m = 0; m < 4; ++m) {
      const int row0 = bm0 + wm + m * 16 + lk * 4;
#pragma unroll
      for (int r = 0; r < 4; ++r) {
        const int row = row0 + r;
        const float vv = bf2f(V[(size_t)row * DH + col]);
        out[(size_t)row * H_DIM + h * DH + col] = acc[m][n][r] * scale * vv;
      }
    }
  }
}

// ---------------- Phase 3: in-place LayerNorm over rows of d_out ----------------
__launch_bounds__(256, 4)
__global__ void ln_kernel(float* __restrict__ out, const float* __restrict__ gamma,
                          const float* __restrict__ beta) {
  const int row = blockIdx.x;
  const int t = threadIdx.x;
  float* p = out + (size_t)row * H_DIM;
  f32x4 x[4];
  float s1 = 0.f, s2 = 0.f;
#pragma unroll
  for (int i = 0; i < 4; ++i) {
    x[i] = *(const f32x4*)&p[t * 4 + i * 1024];
    s1 += x[i].x + x[i].y + x[i].z + x[i].w;
    s2 += x[i].x * x[i].x + x[i].y * x[i].y + x[i].z * x[i].z + x[i].w * x[i].w;
  }
#pragma unroll
  for (int o = 32; o > 0; o >>= 1) {
    s1 += __shfl_down(s1, o);
    s2 += __shfl_down(s2, o);
  }
  __shared__ float w1[4], w2[4];
  if ((t & 63) == 0) { w1[t >> 6] = s1; w2[t >> 6] = s2; }
  __syncthreads();
  const float tot1 = w1[0] + w1[1] + w1[2] + w1[3];
  const float tot2 = w2[0] + w2[1] + w2[2] + w2[3];
  const float mu = tot1 * (1.0f / H_DIM);
  const float var = tot2 * (1.0f / H_DIM) - mu * mu;
  const float rs = rsqrtf(var + 1e-5f);
#pragma unroll
  for (int i = 0; i < 4; ++i) {
    const int c = t * 4 + i * 1024;
    const f32x4 g = *(const f32x4*)&gamma[c];
    const f32x4 b = *(const f32x4*)&beta[c];
    f32x4 y;
    y.x = (x[i].x - mu) * rs * g.x + b.x;
    y.y = (x[i].y - mu) * rs * g.y + b.y;
    y.z = (x[i].z - mu) * rs * g.z + b.z;
    y.w = (x[i].w - mu) * rs * g.w + b.w;
    *(f32x4*)&p[c] = y;
  }
}

extern "C" void kernel_launch(void* const* d_in, const int* in_sizes, int n_in,
                              void* d_out, int out_size, void* d_ws, size_t ws_size,
                              hipStream_t stream) {
  const float* node1 = (const float*)d_in[0];
  const float* node2 = (const float*)d_in[1];
  const float* Wq = (const float*)d_in[2];
  const float* bq = (const float*)d_in[3];
  const float* Wk = (const float*)d_in[4];
  const float* bk = (const float*)d_in[5];
  const float* Wv = (const float*)d_in[6];
  const float* bv = (const float*)d_in[7];
  const float* gamma = (const float*)d_in[8];
  const float* beta = (const float*)d_in[9];
  float* out = (float*)d_out;

  short* qkv = (short*)d_ws;                          // [3][4][1024][1024] bf16 = 24 MB
  short* qb = qkv;
  short* kb = qkv + (size_t)4 * 1024 * 1024;
  short* vb = qkv + (size_t)8 * 1024 * 1024;

  qkv_gemm<<<768, 256, 0, stream>>>(node1, node2, Wq, bq, Wk, bk, Wv, bv, qkv);
  attn_gemm<<<256, 256, 0, stream>>>(qb, kb, vb, out);
  ln_kernel<<<1024, 256, 0, stream>>>(out, gamma, beta);
}